// Round 3
// baseline (1928.005 us; speedup 1.0000x reference)
//
#include <hip/hip_runtime.h>
#include <hip/hip_bf16.h>

// Problem dims
#define B_SZ   8192
#define IN_SZ  1024
#define H1_SZ  2048
#define H2_SZ  2048
#define OUT_SZ 1024
#define NP     8

typedef __bf16 bf16x8 __attribute__((ext_vector_type(8)));
typedef float  f32x4  __attribute__((ext_vector_type(4)));

__device__ __forceinline__ void async_ld16(const void* g, void* l) {
    __builtin_amdgcn_global_load_lds(
        (const __attribute__((address_space(1))) unsigned int*)g,
        (__attribute__((address_space(3))) unsigned int*)l,
        16, 0, 0);
}

// f32 -> bf16 elementwise (8/thread)
__global__ void cast_bf16_k(const float* __restrict__ in, __hip_bfloat16* __restrict__ out) {
    size_t i = ((size_t)blockIdx.x * 256 + threadIdx.x) * 8;
    float4 a = *(const float4*)(in + i);
    float4 b = *(const float4*)(in + i + 4);
    __hip_bfloat16 t[8] = {
        __float2bfloat16(a.x), __float2bfloat16(a.y), __float2bfloat16(a.z), __float2bfloat16(a.w),
        __float2bfloat16(b.x), __float2bfloat16(b.y), __float2bfloat16(b.z), __float2bfloat16(b.w)};
    uint4 u; __builtin_memcpy(&u, t, 16);
    *(uint4*)(out + i) = u;
}

// in [K][N] f32  ->  out [N][K] bf16  (transposed cast, so GEMM B-operand is K-contiguous)
__global__ void transpose_cast_k(const float* __restrict__ in, __hip_bfloat16* __restrict__ out,
                                 int K, int N) {
    __shared__ float tile[32][33];
    int n0 = blockIdx.x * 32, k0 = blockIdx.y * 32;
    int tx = threadIdx.x, ty = threadIdx.y;  // 32 x 8
#pragma unroll
    for (int j = 0; j < 4; ++j)
        tile[ty + j * 8][tx] = in[(size_t)(k0 + ty + j * 8) * N + (n0 + tx)];
    __syncthreads();
#pragma unroll
    for (int j = 0; j < 4; ++j) {
        int nn = ty + j * 8;
        out[(size_t)(n0 + nn) * K + (k0 + tx)] = __float2bfloat16(tile[tx][nn]);
    }
}

// probs[b,:] = softmax(in[b,:] @ S + sb)   — one wave per row
template <typename T>
__global__ void selector_k(const T* __restrict__ in, const float* __restrict__ S,
                           const float* __restrict__ sb, float* __restrict__ probs, int K) {
    int row  = blockIdx.x * blockDim.y + threadIdx.y;
    int lane = threadIdx.x;
    float acc[NP];
#pragma unroll
    for (int p = 0; p < NP; ++p) acc[p] = 0.f;
    const T* xr = in + (size_t)row * K;
    for (int k = lane; k < K; k += 64) {
        float xv;
        if constexpr (sizeof(T) == 2) xv = __bfloat162float(xr[k]);
        else                          xv = (float)xr[k];
        const float* sr = S + (size_t)k * NP;
#pragma unroll
        for (int p = 0; p < NP; ++p) acc[p] += xv * sr[p];
    }
#pragma unroll
    for (int p = 0; p < NP; ++p)
#pragma unroll
        for (int off = 32; off > 0; off >>= 1)
            acc[p] += __shfl_down(acc[p], off, 64);
    if (lane == 0) {
        float v[NP], m = -1e30f;
#pragma unroll
        for (int p = 0; p < NP; ++p) { v[p] = acc[p] + sb[p]; m = fmaxf(m, v[p]); }
        float s = 0.f;
#pragma unroll
        for (int p = 0; p < NP; ++p) { v[p] = expf(v[p] - m); s += v[p]; }
        float inv = 1.f / s;
#pragma unroll
        for (int p = 0; p < NP; ++p) probs[(size_t)row * NP + p] = v[p] * inv;
    }
}

// DRN layer GEMM, A never materialized:
//   C[m,n] = relu( Σ_p probs[m,p]·( Σ_i Xb[m,i]·Wt[n, p*Kx+i] + bexp[p,n] ) )
// Xb [M][Kx] bf16, Wt [N][NP*Kx] bf16 (pre-transposed). probs applied in fp32 at
// p-boundaries on a second accumulator tile. Double-buffered LDS, 1 barrier/iter,
// XOR-swizzled 16B chunks. m-fastest grid (blockIdx.x = m): co-resident blocks
// share the weight panel; Xb is small and cache-resident for everyone.
template <int KXSHIFT>
__global__ __launch_bounds__(256)
void drn_gemm_k(const __hip_bfloat16* __restrict__ Xb, const __hip_bfloat16* __restrict__ Wt,
                int M, int N, const float* __restrict__ probs, const float* __restrict__ bexp,
                __hip_bfloat16* __restrict__ Cout) {
    constexpr int Kx   = 1 << KXSHIFT;
    constexpr int Ktot = NP << KXSHIFT;
    constexpr int mask = Kx - 1;
    __shared__ alignas(16) __hip_bfloat16 As[2 * 128 * 32];
    __shared__ alignas(16) __hip_bfloat16 Bs[2 * 128 * 32];
    __shared__ float Ps[128 * NP];
    const int tid  = threadIdx.x;
    const int wid  = tid >> 6, lane = tid & 63;
    const int quad = lane >> 4, l16 = lane & 15;
    const int waveM = (wid >> 1) << 6, waveN = (wid & 1) << 6;
    const int m0 = blockIdx.x * 128, n0 = blockIdx.y * 128;

    // stage probs panel [128][NP] into LDS (fp32)
    *(f32x4*)&Ps[tid * 4] = *(const f32x4*)&probs[(size_t)m0 * NP + tid * 4];

    f32x4 zero = {0.f, 0.f, 0.f, 0.f};
    f32x4 accp[4][4], acct[4][4];
#pragma unroll
    for (int a = 0; a < 4; ++a)
#pragma unroll
        for (int b = 0; b < 4; ++b) { accp[a][b] = zero; acct[a][b] = zero; }

    // staging: thread t -> LDS bytes [t*16, t*16+16); swizzle on GLOBAL chunk:
    // LDS[row][c] = G[row][c ^ s(row)], s(r) = (r&3)^((r>>2)&3)
    const int srow = tid >> 2;
    const int skc  = (((tid & 3) ^ (srow & 3) ^ ((srow >> 2) & 3)) << 3);
    const __hip_bfloat16* Ag = Xb + (size_t)(m0 + srow) * Kx + skc;
    const __hip_bfloat16* Bg = Wt + (size_t)(n0 + srow) * Ktot + skc;
    const size_t rowStepA = (size_t)64 * Kx;
    const size_t rowStepB = (size_t)64 * Ktot;
    __hip_bfloat16* AsB = As + wid * 512;
    __hip_bfloat16* BsB = Bs + wid * 512;
    const int csel = (quad ^ (l16 & 3) ^ ((l16 >> 2) & 3)) << 3;

    // prologue: stage tile t=0 into buffer 0
    async_ld16(Ag,            AsB);
    async_ld16(Ag + rowStepA, AsB + 2048);
    async_ld16(Bg,            BsB);
    async_ld16(Bg + rowStepB, BsB + 2048);

    for (int t = 0; t < Ktot; t += 32) {
        const int cur = (t >> 5) & 1;
        __syncthreads();   // drains staging into `cur`; protects other buf from last iter's reads

        if (t + 32 < Ktot) {
            const int nb = (1 - cur) * 4096;
            const int an = (t + 32) & mask;   // x column wraps at p-boundary
            async_ld16(Ag + an,                 AsB + nb);
            async_ld16(Ag + an + rowStepA,      AsB + nb + 2048);
            async_ld16(Bg + (t + 32),           BsB + nb);
            async_ld16(Bg + (t + 32) + rowStepB, BsB + nb + 2048);
        }

        const __hip_bfloat16* AsC = As + cur * 4096;
        const __hip_bfloat16* BsC = Bs + cur * 4096;
        bf16x8 af[4], bfr[4];
#pragma unroll
        for (int q = 0; q < 4; ++q) {
            af[q]  = *(const bf16x8*)(AsC + (waveM + q * 16 + l16) * 32 + csel);
            bfr[q] = *(const bf16x8*)(BsC + (waveN + q * 16 + l16) * 32 + csel);
        }
#pragma unroll
        for (int tm = 0; tm < 4; ++tm)
#pragma unroll
            for (int tn = 0; tn < 4; ++tn)
                accp[tm][tn] = __builtin_amdgcn_mfma_f32_16x16x32_bf16(
                    af[tm], bfr[tn], accp[tm][tn], 0, 0, 0);

        if ((t & mask) == Kx - 32) {   // p-boundary: fold expert partial with fp32 probs
            const int p = t >> KXSHIFT;
#pragma unroll
            for (int tm = 0; tm < 4; ++tm)
#pragma unroll
                for (int r = 0; r < 4; ++r) {
                    float pr = Ps[(waveM + tm * 16 + quad * 4 + r) * NP + p];
#pragma unroll
                    for (int tn = 0; tn < 4; ++tn) {
                        acct[tm][tn][r] += pr * accp[tm][tn][r];
                        accp[tm][tn][r] = 0.f;
                    }
                }
        }
    }

    // epilogue: + Σ_p probs·bexp[p,:], ReLU, bf16 store
    const int colb = n0 + waveN + l16;
    __hip_bfloat16* C = Cout;
    float bx[4][NP];
#pragma unroll
    for (int tn = 0; tn < 4; ++tn)
#pragma unroll
        for (int p = 0; p < NP; ++p)
            bx[tn][p] = bexp[(size_t)p * N + colb + tn * 16];
#pragma unroll
    for (int tm = 0; tm < 4; ++tm) {
#pragma unroll
        for (int r = 0; r < 4; ++r) {
            int lr  = waveM + tm * 16 + quad * 4 + r;
            int row = m0 + lr;
            float pv[NP];
#pragma unroll
            for (int p = 0; p < NP; ++p) pv[p] = Ps[lr * NP + p];
#pragma unroll
            for (int tn = 0; tn < 4; ++tn) {
                float bsum = 0.f;
#pragma unroll
                for (int p = 0; p < NP; ++p) bsum += pv[p] * bx[tn][p];
                float v = fmaxf(acct[tm][tn][r] + bsum, 0.f);
                C[(size_t)row * N + colb + tn * 16] = __float2bfloat16(v);
            }
        }
    }
}

// Plain C = A @ Bt^T + bias (f32 out) for the classifier. Double-buffered, swizzled.
__global__ __launch_bounds__(256)
void gemm_bt_k(const __hip_bfloat16* __restrict__ A, const __hip_bfloat16* __restrict__ Bt,
               int M, int N, int K, const float* __restrict__ bias, float* __restrict__ C) {
    __shared__ alignas(16) __hip_bfloat16 As[2 * 128 * 32];
    __shared__ alignas(16) __hip_bfloat16 Bs[2 * 128 * 32];
    const int tid  = threadIdx.x;
    const int wid  = tid >> 6, lane = tid & 63;
    const int quad = lane >> 4, l16 = lane & 15;
    const int waveM = (wid >> 1) << 6, waveN = (wid & 1) << 6;
    const int m0 = blockIdx.x * 128, n0 = blockIdx.y * 128;

    f32x4 zero = {0.f, 0.f, 0.f, 0.f};
    f32x4 acc[4][4];
#pragma unroll
    for (int a = 0; a < 4; ++a)
#pragma unroll
        for (int b = 0; b < 4; ++b) acc[a][b] = zero;

    const int srow = tid >> 2;
    const int skc  = (((tid & 3) ^ (srow & 3) ^ ((srow >> 2) & 3)) << 3);
    const __hip_bfloat16* Ag = A  + (size_t)(m0 + srow) * K + skc;
    const __hip_bfloat16* Bg = Bt + (size_t)(n0 + srow) * K + skc;
    const size_t rowStep = (size_t)64 * K;
    __hip_bfloat16* AsB = As + wid * 512;
    __hip_bfloat16* BsB = Bs + wid * 512;
    const int csel = (quad ^ (l16 & 3) ^ ((l16 >> 2) & 3)) << 3;

    async_ld16(Ag,           AsB);
    async_ld16(Ag + rowStep, AsB + 2048);
    async_ld16(Bg,           BsB);
    async_ld16(Bg + rowStep, BsB + 2048);

    for (int kt = 0; kt < K; kt += 32) {
        const int cur = (kt >> 5) & 1;
        __syncthreads();
        if (kt + 32 < K) {
            const int nb = (1 - cur) * 4096;
            async_ld16(Ag + kt + 32,           AsB + nb);
            async_ld16(Ag + kt + 32 + rowStep, AsB + nb + 2048);
            async_ld16(Bg + kt + 32,           BsB + nb);
            async_ld16(Bg + kt + 32 + rowStep, BsB + nb + 2048);
        }
        const __hip_bfloat16* AsC = As + cur * 4096;
        const __hip_bfloat16* BsC = Bs + cur * 4096;
        bf16x8 af[4], bfr[4];
#pragma unroll
        for (int q = 0; q < 4; ++q) {
            af[q]  = *(const bf16x8*)(AsC + (waveM + q * 16 + l16) * 32 + csel);
            bfr[q] = *(const bf16x8*)(BsC + (waveN + q * 16 + l16) * 32 + csel);
        }
#pragma unroll
        for (int tm = 0; tm < 4; ++tm)
#pragma unroll
            for (int tn = 0; tn < 4; ++tn)
                acc[tm][tn] = __builtin_amdgcn_mfma_f32_16x16x32_bf16(
                    af[tm], bfr[tn], acc[tm][tn], 0, 0, 0);
    }

    const int colb = n0 + waveN + l16;
#pragma unroll
    for (int tm = 0; tm < 4; ++tm)
#pragma unroll
        for (int r = 0; r < 4; ++r) {
            int row = m0 + waveM + tm * 16 + quad * 4 + r;
#pragma unroll
            for (int tn = 0; tn < 4; ++tn)
                C[(size_t)row * N + colb + tn * 16] =
                    acc[tm][tn][r] + bias[colb + tn * 16];
        }
}

extern "C" void kernel_launch(void* const* d_in, const int* in_sizes, int n_in,
                              void* d_out, int out_size, void* d_ws, size_t ws_size,
                              hipStream_t stream) {
    const float* x   = (const float*)d_in[0];
    const float* W1  = (const float*)d_in[1];
    const float* b1  = (const float*)d_in[2];
    const float* S1  = (const float*)d_in[3];
    const float* sb1 = (const float*)d_in[4];
    const float* W2  = (const float*)d_in[5];
    const float* b2  = (const float*)d_in[6];
    const float* S2  = (const float*)d_in[7];
    const float* sb2 = (const float*)d_in[8];
    const float* Wc  = (const float*)d_in[9];
    const float* bc  = (const float*)d_in[10];
    float* out = (float*)d_out;

    char* ws = (char*)d_ws;
    size_t off = 0;
    auto alloc = [&](size_t bytes) {
        char* p = ws + off;
        off += (bytes + 255) & ~(size_t)255;
        return p;
    };
    __hip_bfloat16* W1t = (__hip_bfloat16*)alloc((size_t)H1_SZ * (NP * IN_SZ) * 2);  // 32 MB [2048][8192]
    __hip_bfloat16* W2t = (__hip_bfloat16*)alloc((size_t)H2_SZ * (NP * H1_SZ) * 2);  // 64 MB [2048][16384]
    __hip_bfloat16* Wct = (__hip_bfloat16*)alloc((size_t)OUT_SZ * H2_SZ * 2);        //  4 MB [1024][2048]
    float* probs1       = (float*)alloc((size_t)B_SZ * NP * 4);
    float* probs2       = (float*)alloc((size_t)B_SZ * NP * 4);
    __hip_bfloat16* xb  = (__hip_bfloat16*)alloc((size_t)B_SZ * IN_SZ * 2);          // 16 MB
    __hip_bfloat16* h1  = (__hip_bfloat16*)alloc((size_t)B_SZ * H1_SZ * 2);          // 32 MB
    __hip_bfloat16* h2  = (__hip_bfloat16*)alloc((size_t)B_SZ * H2_SZ * 2);          // 32 MB

    dim3 tb(32, 8);
    transpose_cast_k<<<dim3(H1_SZ / 32, (NP * IN_SZ) / 32), tb, 0, stream>>>(W1, W1t, NP * IN_SZ, H1_SZ);
    transpose_cast_k<<<dim3(H2_SZ / 32, (NP * H1_SZ) / 32), tb, 0, stream>>>(W2, W2t, NP * H1_SZ, H2_SZ);
    transpose_cast_k<<<dim3(OUT_SZ / 32, H2_SZ / 32), tb, 0, stream>>>(Wc, Wct, H2_SZ, OUT_SZ);
    cast_bf16_k<<<(B_SZ * IN_SZ) / (256 * 8), 256, 0, stream>>>(x, xb);

    // layer 1
    selector_k<float><<<B_SZ / 4, dim3(64, 4), 0, stream>>>(x, S1, sb1, probs1, IN_SZ);
    drn_gemm_k<10><<<dim3(B_SZ / 128, H1_SZ / 128), 256, 0, stream>>>(
        xb, W1t, B_SZ, H1_SZ, probs1, b1, h1);

    // layer 2
    selector_k<__hip_bfloat16><<<B_SZ / 4, dim3(64, 4), 0, stream>>>(h1, S2, sb2, probs2, H1_SZ);
    drn_gemm_k<11><<<dim3(B_SZ / 128, H2_SZ / 128), 256, 0, stream>>>(
        h1, W2t, B_SZ, H2_SZ, probs2, b2, h2);

    // classifier
    gemm_bt_k<<<dim3(B_SZ / 128, OUT_SZ / 128), 256, 0, stream>>>(
        h2, Wct, B_SZ, OUT_SZ, H2_SZ, bc, out);
}

// Round 4
// 1447.583 us; speedup vs baseline: 1.3319x; 1.3319x over previous
//
#include <hip/hip_runtime.h>
#include <hip/hip_bf16.h>

// Problem dims
#define B_SZ   8192
#define IN_SZ  1024
#define H1_SZ  2048
#define H2_SZ  2048
#define OUT_SZ 1024
#define NP     8

typedef __bf16 bf16x8 __attribute__((ext_vector_type(8)));
typedef float  f32x4  __attribute__((ext_vector_type(4)));

__device__ __forceinline__ void async_ld16(const void* g, void* l) {
    __builtin_amdgcn_global_load_lds(
        (const __attribute__((address_space(1))) unsigned int*)g,
        (__attribute__((address_space(3))) unsigned int*)l,
        16, 0, 0);
}

__device__ __forceinline__ float bfbits_to_f(unsigned int u) {
    union { unsigned int i; float f; } c;
    c.i = u << 16;
    return c.f;
}

// in [K][N] f32  ->  out [N][K] bf16  (transposed cast, so GEMM B-operand is K-contiguous)
__global__ void transpose_cast_k(const float* __restrict__ in, __hip_bfloat16* __restrict__ out,
                                 int K, int N) {
    __shared__ float tile[32][33];
    int n0 = blockIdx.x * 32, k0 = blockIdx.y * 32;
    int tx = threadIdx.x, ty = threadIdx.y;  // 32 x 8
#pragma unroll
    for (int j = 0; j < 4; ++j)
        tile[ty + j * 8][tx] = in[(size_t)(k0 + ty + j * 8) * N + (n0 + tx)];
    __syncthreads();
#pragma unroll
    for (int j = 0; j < 4; ++j) {
        int nn = ty + j * 8;
        out[(size_t)(n0 + nn) * K + (k0 + tx)] = __float2bfloat16(tile[tx][nn]);
    }
}

// probs[b,:] = softmax(in[b,:] @ S + sb)   — one wave per row
template <typename T>
__global__ void selector_k(const T* __restrict__ in, const float* __restrict__ S,
                           const float* __restrict__ sb, float* __restrict__ probs, int K) {
    int row  = blockIdx.x * blockDim.y + threadIdx.y;
    int lane = threadIdx.x;
    float acc[NP];
#pragma unroll
    for (int p = 0; p < NP; ++p) acc[p] = 0.f;
    const T* xr = in + (size_t)row * K;
    for (int k = lane; k < K; k += 64) {
        float xv;
        if constexpr (sizeof(T) == 2) xv = __bfloat162float(xr[k]);
        else                          xv = (float)xr[k];
        const float* sr = S + (size_t)k * NP;
#pragma unroll
        for (int p = 0; p < NP; ++p) acc[p] += xv * sr[p];
    }
#pragma unroll
    for (int p = 0; p < NP; ++p)
#pragma unroll
        for (int off = 32; off > 0; off >>= 1)
            acc[p] += __shfl_down(acc[p], off, 64);
    if (lane == 0) {
        float v[NP], m = -1e30f;
#pragma unroll
        for (int p = 0; p < NP; ++p) { v[p] = acc[p] + sb[p]; m = fmaxf(m, v[p]); }
        float s = 0.f;
#pragma unroll
        for (int p = 0; p < NP; ++p) { v[p] = expf(v[p] - m); s += v[p]; }
        float inv = 1.f / s;
#pragma unroll
        for (int p = 0; p < NP; ++p) probs[(size_t)row * NP + p] = v[p] * inv;
    }
}

// A[b, p*K + i] = bf16(probs[b,p] * in[b,i])    (8 elems / thread, 16B stores; blockDim 128)
template <typename T>
__global__ void build_a_k(const T* __restrict__ in, const float* __restrict__ probs,
                          __hip_bfloat16* __restrict__ A, int K) {
    int b = blockIdx.y;
    int i = (blockIdx.x * 128 + threadIdx.x) * 8;
    float pv[NP];
#pragma unroll
    for (int p = 0; p < NP; ++p) pv[p] = probs[(size_t)b * NP + p];
    float xv[8];
    if constexpr (sizeof(T) == 2) {
        uint4 u = *(const uint4*)((const unsigned short*)in + (size_t)b * K + i);
        xv[0] = bfbits_to_f(u.x & 0xffff); xv[1] = bfbits_to_f(u.x >> 16);
        xv[2] = bfbits_to_f(u.y & 0xffff); xv[3] = bfbits_to_f(u.y >> 16);
        xv[4] = bfbits_to_f(u.z & 0xffff); xv[5] = bfbits_to_f(u.z >> 16);
        xv[6] = bfbits_to_f(u.w & 0xffff); xv[7] = bfbits_to_f(u.w >> 16);
    } else {
        const float* xp = (const float*)in + (size_t)b * K + i;
        float4 f0 = *(const float4*)xp;
        float4 f1 = *(const float4*)(xp + 4);
        xv[0] = f0.x; xv[1] = f0.y; xv[2] = f0.z; xv[3] = f0.w;
        xv[4] = f1.x; xv[5] = f1.y; xv[6] = f1.z; xv[7] = f1.w;
    }
    size_t base = (size_t)b * ((size_t)NP * K);
#pragma unroll
    for (int p = 0; p < NP; ++p) {
        __hip_bfloat16 tmp[8];
#pragma unroll
        for (int j = 0; j < 8; ++j) tmp[j] = __float2bfloat16(pv[p] * xv[j]);
        uint4 u4;
        __builtin_memcpy(&u4, tmp, 16);
        *(uint4*)(A + base + (size_t)p * K + i) = u4;
    }
}

// DRN layer GEMM: C = relu(A @ Wt^T + Σ_p probs·bexp[p,:]), bf16 out.
// A [M][K] bf16 (probs pre-folded), Wt [N][K] bf16.
// Block tile 128M x 256N, 4 waves of 64x128 (acc[4][8]) -> grid 512 = 2 blocks/CU,
// single dispatch round, no tail. Double-buffered LDS, XOR-swizzled 16B chunks.
// XCD-aware mapping: id&7 = XCD (round-robin dispatch); each XCD gets a contiguous
// 8-M-panel range, n-fastest within, so an A panel's sharers live on ONE L2.
__global__ __launch_bounds__(256, 2)
void drn_gemm2_k(const __hip_bfloat16* __restrict__ A, const __hip_bfloat16* __restrict__ Wt,
                 int N, int K, const float* __restrict__ probs,
                 const float* __restrict__ bexp, __hip_bfloat16* __restrict__ C) {
    __shared__ alignas(16) __hip_bfloat16 As[2 * 128 * 32];   // 16 KB
    __shared__ alignas(16) __hip_bfloat16 Bs[2 * 256 * 32];   // 32 KB
    const int tid  = threadIdx.x;
    const int wid  = tid >> 6, lane = tid & 63;
    const int quad = lane >> 4, l16 = lane & 15;
    const int waveM = (wid >> 1) * 64, waveN = (wid & 1) * 128;

    const int g   = blockIdx.x;
    const int xcd = g & 7, s = g >> 3;          // grid = 64 Mb x 8 Nb = 512
    const int mb  = xcd * 8 + (s >> 3);         // 8 M-panels per XCD
    const int nb  = s & 7;
    const int m0  = mb * 128, n0 = nb * 256;

    f32x4 zero = {0.f, 0.f, 0.f, 0.f};
    f32x4 acc[4][8];
#pragma unroll
    for (int a = 0; a < 4; ++a)
#pragma unroll
        for (int b = 0; b < 8; ++b) acc[a][b] = zero;

    // staging: thread t -> LDS chunk t*16B; swizzle on GLOBAL chunk:
    // LDS[row][c] = G[row][c ^ s(row)], s(r) = (r&3)^((r>>2)&3)
    const int srow = tid >> 2;
    const int skc  = (((tid & 3) ^ (srow & 3) ^ ((srow >> 2) & 3)) << 3);
    const __hip_bfloat16* Ag = A  + (size_t)(m0 + srow) * K + skc;
    const __hip_bfloat16* Bg = Wt + (size_t)(n0 + srow) * K + skc;
    const size_t rs = (size_t)64 * K;
    __hip_bfloat16* AsB = As + wid * 512;
    __hip_bfloat16* BsB = Bs + wid * 512;
    const int csel = ((quad ^ (l16 & 3) ^ ((l16 >> 2) & 3)) << 3);

    // prologue: tile 0 into buffer 0
    async_ld16(Ag,          AsB);
    async_ld16(Ag + rs,     AsB + 2048);
    async_ld16(Bg,          BsB);
    async_ld16(Bg + rs,     BsB + 2048);
    async_ld16(Bg + 2 * rs, BsB + 4096);
    async_ld16(Bg + 3 * rs, BsB + 6144);

    for (int kt = 0; kt < K; kt += 32) {
        const int cur = (kt >> 5) & 1;
        __syncthreads();   // drains staging into `cur`; protects other buf

        if (kt + 32 < K) {
            const int na = (1 - cur) * 4096, nbuf = (1 - cur) * 8192;
            async_ld16(Ag + kt + 32,          AsB + na);
            async_ld16(Ag + kt + 32 + rs,     AsB + na + 2048);
            async_ld16(Bg + kt + 32,          BsB + nbuf);
            async_ld16(Bg + kt + 32 + rs,     BsB + nbuf + 2048);
            async_ld16(Bg + kt + 32 + 2 * rs, BsB + nbuf + 4096);
            async_ld16(Bg + kt + 32 + 3 * rs, BsB + nbuf + 6144);
        }

        const __hip_bfloat16* AsC = As + cur * 4096;
        const __hip_bfloat16* BsC = Bs + cur * 8192;
        bf16x8 af[4], bfr[8];
#pragma unroll
        for (int q = 0; q < 4; ++q)
            af[q] = *(const bf16x8*)(AsC + (waveM + q * 16 + l16) * 32 + csel);
#pragma unroll
        for (int q = 0; q < 8; ++q)
            bfr[q] = *(const bf16x8*)(BsC + (waveN + q * 16 + l16) * 32 + csel);
#pragma unroll
        for (int tm = 0; tm < 4; ++tm)
#pragma unroll
            for (int tn = 0; tn < 8; ++tn)
                acc[tm][tn] = __builtin_amdgcn_mfma_f32_16x16x32_bf16(
                    af[tm], bfr[tn], acc[tm][tn], 0, 0, 0);
    }

    // epilogue: + Σ_p probs·bexp[p,:], ReLU, bf16 store
    const int colb = n0 + waveN + l16;
    float bx[8][NP];
#pragma unroll
    for (int tn = 0; tn < 8; ++tn)
#pragma unroll
        for (int p = 0; p < NP; ++p)
            bx[tn][p] = bexp[(size_t)p * N + colb + tn * 16];
#pragma unroll
    for (int tm = 0; tm < 4; ++tm) {
#pragma unroll
        for (int r = 0; r < 4; ++r) {
            int row = m0 + waveM + tm * 16 + quad * 4 + r;
            const float* pr = probs + (size_t)row * NP;
            f32x4 p0 = *(const f32x4*)pr;
            f32x4 p1 = *(const f32x4*)(pr + 4);
            float pv[NP] = {p0[0], p0[1], p0[2], p0[3], p1[0], p1[1], p1[2], p1[3]};
#pragma unroll
            for (int tn = 0; tn < 8; ++tn) {
                float bsum = 0.f;
#pragma unroll
                for (int p = 0; p < NP; ++p) bsum += pv[p] * bx[tn][p];
                float v = fmaxf(acc[tm][tn][r] + bsum, 0.f);
                C[(size_t)row * N + colb + tn * 16] = __float2bfloat16(v);
            }
        }
    }
}

// Plain C = A @ Bt^T + bias (f32 out) for the classifier. 128x128, dbuf, swizzled.
__global__ __launch_bounds__(256)
void gemm_bt_k(const __hip_bfloat16* __restrict__ A, const __hip_bfloat16* __restrict__ Bt,
               int M, int N, int K, const float* __restrict__ bias, float* __restrict__ C) {
    __shared__ alignas(16) __hip_bfloat16 As[2 * 128 * 32];
    __shared__ alignas(16) __hip_bfloat16 Bs[2 * 128 * 32];
    const int tid  = threadIdx.x;
    const int wid  = tid >> 6, lane = tid & 63;
    const int quad = lane >> 4, l16 = lane & 15;
    const int waveM = (wid >> 1) << 6, waveN = (wid & 1) << 6;
    const int m0 = blockIdx.x * 128, n0 = blockIdx.y * 128;

    f32x4 zero = {0.f, 0.f, 0.f, 0.f};
    f32x4 acc[4][4];
#pragma unroll
    for (int a = 0; a < 4; ++a)
#pragma unroll
        for (int b = 0; b < 4; ++b) acc[a][b] = zero;

    const int srow = tid >> 2;
    const int skc  = (((tid & 3) ^ (srow & 3) ^ ((srow >> 2) & 3)) << 3);
    const __hip_bfloat16* Ag = A  + (size_t)(m0 + srow) * K + skc;
    const __hip_bfloat16* Bg = Bt + (size_t)(n0 + srow) * K + skc;
    const size_t rowStep = (size_t)64 * K;
    __hip_bfloat16* AsB = As + wid * 512;
    __hip_bfloat16* BsB = Bs + wid * 512;
    const int csel = (quad ^ (l16 & 3) ^ ((l16 >> 2) & 3)) << 3;

    async_ld16(Ag,           AsB);
    async_ld16(Ag + rowStep, AsB + 2048);
    async_ld16(Bg,           BsB);
    async_ld16(Bg + rowStep, BsB + 2048);

    for (int kt = 0; kt < K; kt += 32) {
        const int cur = (kt >> 5) & 1;
        __syncthreads();
        if (kt + 32 < K) {
            const int nb = (1 - cur) * 4096;
            async_ld16(Ag + kt + 32,           AsB + nb);
            async_ld16(Ag + kt + 32 + rowStep, AsB + nb + 2048);
            async_ld16(Bg + kt + 32,           BsB + nb);
            async_ld16(Bg + kt + 32 + rowStep, BsB + nb + 2048);
        }
        const __hip_bfloat16* AsC = As + cur * 4096;
        const __hip_bfloat16* BsC = Bs + cur * 4096;
        bf16x8 af[4], bfr[4];
#pragma unroll
        for (int q = 0; q < 4; ++q) {
            af[q]  = *(const bf16x8*)(AsC + (waveM + q * 16 + l16) * 32 + csel);
            bfr[q] = *(const bf16x8*)(BsC + (waveN + q * 16 + l16) * 32 + csel);
        }
#pragma unroll
        for (int tm = 0; tm < 4; ++tm)
#pragma unroll
            for (int tn = 0; tn < 4; ++tn)
                acc[tm][tn] = __builtin_amdgcn_mfma_f32_16x16x32_bf16(
                    af[tm], bfr[tn], acc[tm][tn], 0, 0, 0);
    }

    const int colb = n0 + waveN + l16;
#pragma unroll
    for (int tm = 0; tm < 4; ++tm)
#pragma unroll
        for (int r = 0; r < 4; ++r) {
            int row = m0 + waveM + tm * 16 + quad * 4 + r;
#pragma unroll
            for (int tn = 0; tn < 4; ++tn)
                C[(size_t)row * N + colb + tn * 16] =
                    acc[tm][tn][r] + bias[colb + tn * 16];
        }
}

extern "C" void kernel_launch(void* const* d_in, const int* in_sizes, int n_in,
                              void* d_out, int out_size, void* d_ws, size_t ws_size,
                              hipStream_t stream) {
    const float* x   = (const float*)d_in[0];
    const float* W1  = (const float*)d_in[1];
    const float* b1  = (const float*)d_in[2];
    const float* S1  = (const float*)d_in[3];
    const float* sb1 = (const float*)d_in[4];
    const float* W2  = (const float*)d_in[5];
    const float* b2  = (const float*)d_in[6];
    const float* S2  = (const float*)d_in[7];
    const float* sb2 = (const float*)d_in[8];
    const float* Wc  = (const float*)d_in[9];
    const float* bc  = (const float*)d_in[10];
    float* out = (float*)d_out;

    char* ws = (char*)d_ws;
    size_t off = 0;
    auto alloc = [&](size_t bytes) {
        char* p = ws + off;
        off += (bytes + 255) & ~(size_t)255;
        return p;
    };
    __hip_bfloat16* W1t = (__hip_bfloat16*)alloc((size_t)H1_SZ * (NP * IN_SZ) * 2);  // 32 MB
    __hip_bfloat16* W2t = (__hip_bfloat16*)alloc((size_t)H2_SZ * (NP * H1_SZ) * 2);  // 64 MB
    __hip_bfloat16* Wct = (__hip_bfloat16*)alloc((size_t)OUT_SZ * H2_SZ * 2);        //  4 MB
    float* probs1       = (float*)alloc((size_t)B_SZ * NP * 4);
    float* probs2       = (float*)alloc((size_t)B_SZ * NP * 4);
    __hip_bfloat16* h1  = (__hip_bfloat16*)alloc((size_t)B_SZ * H1_SZ * 2);          // 32 MB
    __hip_bfloat16* h2  = (__hip_bfloat16*)alloc((size_t)B_SZ * H2_SZ * 2);          // 32 MB
    __hip_bfloat16* Abuf= (__hip_bfloat16*)alloc((size_t)B_SZ * (NP * H1_SZ) * 2);   // 256 MB (shared)

    dim3 tb(32, 8);
    transpose_cast_k<<<dim3(H1_SZ / 32, (NP * IN_SZ) / 32), tb, 0, stream>>>(W1, W1t, NP * IN_SZ, H1_SZ);
    transpose_cast_k<<<dim3(H2_SZ / 32, (NP * H1_SZ) / 32), tb, 0, stream>>>(W2, W2t, NP * H1_SZ, H2_SZ);
    transpose_cast_k<<<dim3(OUT_SZ / 32, H2_SZ / 32), tb, 0, stream>>>(Wc, Wct, H2_SZ, OUT_SZ);

    // layer 1
    selector_k<float><<<B_SZ / 4, dim3(64, 4), 0, stream>>>(x, S1, sb1, probs1, IN_SZ);
    build_a_k<float><<<dim3(IN_SZ / 1024, B_SZ), 128, 0, stream>>>(x, probs1, Abuf, IN_SZ);
    drn_gemm2_k<<<(B_SZ / 128) * (H1_SZ / 256), 256, 0, stream>>>(
        Abuf, W1t, H1_SZ, NP * IN_SZ, probs1, b1, h1);

    // layer 2
    selector_k<__hip_bfloat16><<<B_SZ / 4, dim3(64, 4), 0, stream>>>(h1, S2, sb2, probs2, H1_SZ);
    build_a_k<__hip_bfloat16><<<dim3(H1_SZ / 1024, B_SZ), 128, 0, stream>>>(h1, probs2, Abuf, H1_SZ);
    drn_gemm2_k<<<(B_SZ / 128) * (H2_SZ / 256), 256, 0, stream>>>(
        Abuf, W2t, H2_SZ, NP * H1_SZ, probs2, b2, h2);

    // classifier
    gemm_bt_k<<<dim3(B_SZ / 128, OUT_SZ / 128), 256, 0, stream>>>(
        h2, Wct, B_SZ, OUT_SZ, H2_SZ, bc, out);
}